// Round 17
// baseline (432.130 us; speedup 1.0000x reference)
//
#include <hip/hip_runtime.h>
#include <stdint.h>

typedef unsigned short u16;
typedef short bf16x8 __attribute__((ext_vector_type(8)));
typedef float f32x4 __attribute__((ext_vector_type(4)));
typedef float f32x16 __attribute__((ext_vector_type(16)));
typedef u16 u16x4 __attribute__((ext_vector_type(4)));
typedef u16 u16x8 __attribute__((ext_vector_type(8)));

#define LOG2E 1.4426950408889634f
#define QSCALE (0.125f * LOG2E)

__device__ __forceinline__ u16 f2bf(float f) {
  union { float f; uint32_t u; } x; x.f = f;
  uint32_t r = x.u + 0x7fffu + ((x.u >> 16) & 1u);
  return (u16)(r >> 16);
}
__device__ __forceinline__ u16 f2bf_ru(float f) {
  union { float f; uint32_t u; } x; x.f = f;
  return (u16)((x.u + 0x8000u) >> 16);
}
__device__ __forceinline__ float bf2f(u16 h) {
  union { uint32_t u; float f; } x; x.u = ((uint32_t)h) << 16;
  return x.f;
}
__device__ __forceinline__ uint32_t cvtpk(float lo, float hi) {
  uint32_t r;
  asm("v_cvt_pk_bf16_f32 %0, %1, %2" : "=v"(r) : "v"(lo), "v"(hi));
  return r;
}
// 16B-granule XOR swizzle (involution, low 3 bits of granule index)
__device__ __forceinline__ int swz3(int row) { return (row ^ (row >> 3)) & 7; }

__device__ __forceinline__ void gload_lds16(const void* g, void* lds) {
  __builtin_amdgcn_global_load_lds(
      (const __attribute__((address_space(1))) void*)g,
      (__attribute__((address_space(3))) void*)lds, 16, 0, 0);
}

// ---------------- cast f32 -> bf16 (8 elems/thread) ----------------
__global__ __launch_bounds__(256) void cast_bf16(const float* __restrict__ in,
                                                 u16* __restrict__ out, int n8) {
  int i = blockIdx.x * 256 + threadIdx.x;
  const int stride = gridDim.x * 256;
  for (; i < n8; i += stride) {
    const f32x4* p = (const f32x4*)in + (size_t)i * 2;
    f32x4 a = p[0], b = p[1];
    u16x8 o;
    o[0] = f2bf(a[0]); o[1] = f2bf(a[1]); o[2] = f2bf(a[2]); o[3] = f2bf(a[3]);
    o[4] = f2bf(b[0]); o[5] = f2bf(b[1]); o[6] = f2bf(b[2]); o[7] = f2bf(b[3]);
    ((u16x8*)out)[i] = o;
  }
}

// ---------------- concat 3 bias vectors; bq pre-scaled by QSCALE ----------------
__global__ __launch_bounds__(256) void concat3(const float* __restrict__ a,
                                               const float* __restrict__ b,
                                               const float* __restrict__ c,
                                               float* __restrict__ o) {
  int i = blockIdx.x * 256 + threadIdx.x;
  if (i < 3072)
    o[i] = i < 1024 ? a[i] * QSCALE : (i < 2048 ? b[i - 1024] : c[i - 2048]);
}

// ---------------- transpose + cast + scale: W[R][C] f32 -> WT[C][R] bf16 ----------------
__global__ __launch_bounds__(256) void transpose_cast(const float* __restrict__ in,
                                                      u16* __restrict__ out, int R, int C,
                                                      float scale) {
  __shared__ float tile[32][33];
  const int bc = blockIdx.x * 32, br = blockIdx.y * 32;
  const int tx = threadIdx.x & 31, ty = threadIdx.x >> 5;  // 32 x 8
#pragma unroll
  for (int i = 0; i < 32; i += 8)
    tile[ty + i][tx] = in[(size_t)(br + ty + i) * C + bc + tx];
  __syncthreads();
#pragma unroll
  for (int i = 0; i < 32; i += 8)
    out[(size_t)(bc + ty + i) * R + br + tx] = f2bf(tile[tx][ty + i] * scale);
}

// ---------------- V transpose: QKV V-part [s][dh] -> Vt_g[b*16+h][dh][S] ----------------
__global__ __launch_bounds__(256) void vtrans(const u16* __restrict__ QKV,
                                              u16* __restrict__ Vtg) {
  __shared__ u16 tl[64][65];
  const int t = threadIdx.x;
  const int sblk = blockIdx.x, h = blockIdx.y, b = blockIdx.z;
  const int s0 = sblk * 64;
  const size_t ibase = ((size_t)b * 2048) * 3072 + 2048 + h * 64;
#pragma unroll
  for (int i = 0; i < 2; i++) {
    const int idx = i * 256 + t;
    const int sl = idx >> 3, d0 = (idx & 7) * 8;
    bf16x8 v = *(const bf16x8*)&QKV[ibase + (size_t)(s0 + sl) * 3072 + d0];
#pragma unroll
    for (int e = 0; e < 8; e++) tl[d0 + e][sl] = (u16)v[e];
  }
  __syncthreads();
  const size_t ob = ((size_t)(b * 16 + h) * 64) * 2048;
#pragma unroll
  for (int i = 0; i < 2; i++) {
    const int idx = i * 256 + t;
    const int r = idx >> 3, c0 = (idx & 7) * 8;
    u16x8 o;
#pragma unroll
    for (int e = 0; e < 8; e++) o[e] = tl[r][c0 + e];
    *(u16x8*)&Vtg[ob + (size_t)r * 2048 + s0 + c0] = o;
  }
}

// ---------------- GEMM 256x256, 4-phase + counted vmcnt, 32x32 MFMA ----------------
// 8 waves (2M x 4N), per-wave 128x64 = 4x2 frags of 32x32. Per K-tile:
// 16 A + 8 B ds_read_b128 (same as 16x16 version), 32 mfma_32x32x16
// (256 pipe-cyc vs 320 for 64x 16x16). Staging + vmcnt math identical
// to the verified round-7/10 schedule. Frag layouts = attn_fwd-verified:
// A row=lane&31 k=hf*8, B col=lane&31, D row=(reg&3)+8(reg>>2)+4hf col=lane&31.
template <int RELU>
__global__ __launch_bounds__(512, 2) void gemm8p(const u16* __restrict__ A,
                                                 const u16* __restrict__ BT,
                                                 const float* __restrict__ bias,
                                                 u16* __restrict__ Cb,
                                                 int M, int N, int K, int nbx) {
  __shared__ u16 As[2][256 * 64];
  __shared__ u16 Bs[2][256 * 64];
  const int t = threadIdx.x;
  const int w = t >> 6, lane = t & 63;
  const int l5 = lane & 31, hf = lane >> 5;
  const int wr = w >> 2, wc = w & 3;
  int bid = (int)blockIdx.x;
  const int cpx = (int)gridDim.x >> 3;
  bid = (bid & 7) * cpx + (bid >> 3);
  const int m0 = (bid / nbx) * 256, n0 = (bid % nbx) * 256;
  const int NT = K >> 6;
  const int row64 = t >> 3;
  const int colp = ((t & 7) ^ swz3(row64)) << 3;

#define STG_A(buf, tile, q) \
  gload_lds16(A + (size_t)(m0 + (q)*64 + row64) * K + ((tile) << 6) + colp, \
              &As[buf][(q)*4096 + w * 512])
#define STG_B(buf, tile, q) \
  gload_lds16(BT + (size_t)(n0 + (q)*64 + row64) * K + ((tile) << 6) + colp, \
              &Bs[buf][(q)*4096 + w * 512])
#define LDA32(dst, mfi, kb) { const int r_ = wr * 128 + (mfi)*32 + l5; \
  dst = *(const bf16x8*)&As[cur][r_ * 64 + (((((kb) << 1) + hf) ^ swz3(r_)) << 3)]; }
#define LDB32(dst, nfi, kb) { const int r_ = wc * 64 + (nfi)*32 + l5; \
  dst = *(const bf16x8*)&Bs[cur][r_ * 64 + (((((kb) << 1) + hf) ^ swz3(r_)) << 3)]; }
#define MFMA32(mh, nfi, barr) \
  __builtin_amdgcn_s_setprio(1); \
  _Pragma("unroll") for (int kb = 0; kb < 4; kb++) \
  _Pragma("unroll") for (int i = 0; i < 2; i++) \
    acc[((mh)*2 + i) * 2 + (nfi)] = __builtin_amdgcn_mfma_f32_32x32x16_bf16( \
        af[i][kb], barr[kb], acc[((mh)*2 + i) * 2 + (nfi)], 0, 0, 0); \
  __builtin_amdgcn_s_setprio(0);
#define BAR1() __builtin_amdgcn_s_barrier(); \
  asm volatile("s_waitcnt lgkmcnt(0)" ::: "memory"); \
  __builtin_amdgcn_sched_barrier(0)

  f32x16 acc[8];  // (mf)*2 + nf, mf 0..3, nf 0..1 — static indices only
#pragma unroll
  for (int i = 0; i < 8; i++)
#pragma unroll
    for (int j = 0; j < 16; j++) acc[i][j] = 0.f;

  STG_A(0, 0, 0); STG_A(0, 0, 2);
  STG_B(0, 0, 0); STG_B(0, 0, 1); STG_B(0, 0, 2); STG_B(0, 0, 3);
  STG_A(0, 0, 1); STG_A(0, 0, 3);
  asm volatile("s_waitcnt vmcnt(2)" ::: "memory");
  __builtin_amdgcn_s_barrier();

  for (int tile = 0; tile < NT; ++tile) {
    const int cur = tile & 1, nxt = cur ^ 1;
    const bool hn = (tile + 1) < NT;
    bf16x8 af[2][4], b0[4], b1[4];
    // ---- phase 0: (mh0, nf0) — load af(mf0-1) + b0 ----
#pragma unroll
    for (int kb = 0; kb < 4; kb++) { LDA32(af[0][kb], 0, kb); LDA32(af[1][kb], 1, kb); }
#pragma unroll
    for (int kb = 0; kb < 4; kb++) { LDB32(b0[kb], 0, kb); }
    if (hn) { STG_A(nxt, tile + 1, 0); STG_A(nxt, tile + 1, 2); }
    BAR1();
    MFMA32(0, 0, b0);
    __builtin_amdgcn_s_barrier();
    // ---- phase 1: (mh0, nf1) — load b1; af reused ----
#pragma unroll
    for (int kb = 0; kb < 4; kb++) { LDB32(b1[kb], 1, kb); }
    if (hn) { STG_B(nxt, tile + 1, 0); STG_B(nxt, tile + 1, 1); }
    BAR1();
    MFMA32(0, 1, b1);
    if (hn) { asm volatile("s_waitcnt vmcnt(4)" ::: "memory"); }
    else    { asm volatile("s_waitcnt vmcnt(0)" ::: "memory"); }
    __builtin_amdgcn_s_barrier();
    // ---- phase 2: (mh1, nf0) — load af(mf2-3); b0 reused ----
#pragma unroll
    for (int kb = 0; kb < 4; kb++) { LDA32(af[0][kb], 2, kb); LDA32(af[1][kb], 3, kb); }
    if (hn) { STG_B(nxt, tile + 1, 2); STG_B(nxt, tile + 1, 3); }
    BAR1();
    MFMA32(1, 0, b0);
    __builtin_amdgcn_s_barrier();
    // ---- phase 3: (mh1, nf1) — zero ds_reads; af + b1 reused ----
    if (hn) { STG_A(nxt, tile + 1, 1); STG_A(nxt, tile + 1, 3); }
    BAR1();
    MFMA32(1, 1, b1);
    if (hn) { asm volatile("s_waitcnt vmcnt(2)" ::: "memory"); }
    __builtin_amdgcn_s_barrier();
  }
#undef STG_A
#undef STG_B
#undef LDA32
#undef LDB32
#undef MFMA32
#undef BAR1

  // epilogue: col = n0+wc*64+nf*32+l5, row = m0+wr*128+mf*32+(reg&3)+8(reg>>2)+4hf
#pragma unroll
  for (int mf = 0; mf < 4; mf++) {
#pragma unroll
    for (int nf = 0; nf < 2; nf++) {
      const int c = n0 + wc * 64 + nf * 32 + l5;
      const float bv = bias[c];
#pragma unroll
      for (int reg = 0; reg < 16; reg++) {
        const int r = m0 + wr * 128 + mf * 32 + (reg & 3) + 8 * (reg >> 2) + 4 * hf;
        float v = acc[mf * 2 + nf][reg] + bv;
        if (RELU) v = fmaxf(v, 0.f);
        Cb[(size_t)r * N + c] = f2bf(v);
      }
    }
  }
}

// ---------------- GEMM 128x256, 2-phase + counted vmcnt (N=1024 shapes) ----------------
template <int RELU>
__global__ __launch_bounds__(512, 2) void gemm8n(const u16* __restrict__ A,
                                                 const u16* __restrict__ BT,
                                                 const float* __restrict__ bias,
                                                 u16* __restrict__ Cb,
                                                 int M, int N, int K, int nbx) {
  __shared__ u16 As[2][128 * 64];
  __shared__ u16 Bs[2][256 * 64];
  const int t = threadIdx.x;
  const int w = t >> 6, lane = t & 63;
  const int la = lane & 15, lb = lane >> 4;
  const int wr = w >> 2, wc = w & 3;
  int bid = (int)blockIdx.x;
  const int cpx = (int)gridDim.x >> 3;
  bid = (bid & 7) * cpx + (bid >> 3);
  const int m0 = (bid / nbx) * 128, n0 = (bid % nbx) * 256;
  const int NT = K >> 6;
  const int rowA = t >> 3;
  const int colpA = ((t & 7) ^ swz3(rowA)) << 3;

#define STG_An(buf, tile, q) \
  gload_lds16(A + (size_t)(m0 + (q)*64 + rowA) * K + ((tile) << 6) + colpA, \
              &As[buf][(q)*4096 + t * 8])
#define STG_Bn(buf, tile, c, i) { \
  const int r32_ = (i)*64 + (t >> 3); \
  const int R_ = ((r32_ >> 5) << 6) + (c)*32 + (r32_ & 31); \
  const int cp_ = ((t & 7) ^ swz3(R_)) << 3; \
  gload_lds16(BT + (size_t)(n0 + R_) * K + ((tile) << 6) + cp_, \
              &Bs[buf][R_ * 64 + (t & 7) * 8]); }
#define LDAn(dst, mf, ks) { const int r_ = wr * 64 + (mf)*16 + la; \
  dst = *(const bf16x8*)&As[cur][r_ * 64 + (((((ks) << 2) + lb) ^ swz3(r_)) << 3)]; }
#define LDBn(dst, nf, ks) { const int r_ = wc * 64 + (nf)*16 + la; \
  dst = *(const bf16x8*)&Bs[cur][r_ * 64 + (((((ks) << 2) + lb) ^ swz3(r_)) << 3)]; }
#define MFMAn(nh, barr) \
  __builtin_amdgcn_s_setprio(1); \
  _Pragma("unroll") for (int ks = 0; ks < 2; ks++) \
  _Pragma("unroll") for (int i = 0; i < 4; i++) \
  _Pragma("unroll") for (int j = 0; j < 2; j++) \
    acc[i][(nh)*2 + j] = __builtin_amdgcn_mfma_f32_16x16x32_bf16( \
        af[i][ks], barr[j][ks], acc[i][(nh)*2 + j], 0, 0, 0); \
  __builtin_amdgcn_s_setprio(0);
#define BARn() __builtin_amdgcn_s_barrier(); \
  asm volatile("s_waitcnt lgkmcnt(0)" ::: "memory"); \
  __builtin_amdgcn_sched_barrier(0)

  f32x4 acc[4][4];
#pragma unroll
  for (int i = 0; i < 4; i++)
#pragma unroll
    for (int j = 0; j < 4; j++) acc[i][j] = (f32x4){0.f, 0.f, 0.f, 0.f};

  STG_Bn(0, 0, 0, 0); STG_Bn(0, 0, 0, 1); STG_An(0, 0, 0);
  STG_An(0, 0, 1); STG_Bn(0, 0, 1, 0); STG_Bn(0, 0, 1, 1);
  asm volatile("s_waitcnt vmcnt(0)" ::: "memory");
  __builtin_amdgcn_s_barrier();

  for (int tile = 0; tile < NT; ++tile) {
    const int cur = tile & 1, nxt = cur ^ 1;
    const bool hn = (tile + 1) < NT;
    bf16x8 af[4][2], b0[2][2], b1[2][2];
#pragma unroll
    for (int i = 0; i < 4; i++) { LDAn(af[i][0], i, 0); LDAn(af[i][1], i, 1); }
#pragma unroll
    for (int j = 0; j < 2; j++) { LDBn(b0[j][0], j, 0); LDBn(b0[j][1], j, 1); }
    if (hn) { STG_Bn(nxt, tile + 1, 0, 0); STG_Bn(nxt, tile + 1, 0, 1); STG_An(nxt, tile + 1, 0); }
    BARn();
    MFMAn(0, b0);
    if (hn) { asm volatile("s_waitcnt vmcnt(3)" ::: "memory"); }
    else    { asm volatile("s_waitcnt vmcnt(0)" ::: "memory"); }
    __builtin_amdgcn_s_barrier();
#pragma unroll
    for (int j = 0; j < 2; j++) { LDBn(b1[j][0], 2 + j, 0); LDBn(b1[j][1], 2 + j, 1); }
    if (hn) { STG_An(nxt, tile + 1, 1); STG_Bn(nxt, tile + 1, 1, 0); STG_Bn(nxt, tile + 1, 1, 1); }
    BARn();
    MFMAn(1, b1);
    if (hn) { asm volatile("s_waitcnt vmcnt(2)" ::: "memory"); }
    __builtin_amdgcn_s_barrier();
  }
#undef STG_An
#undef STG_Bn
#undef LDAn
#undef LDBn
#undef MFMAn
#undef BARn

#pragma unroll
  for (int mf = 0; mf < 4; mf++) {
    const int r = m0 + wr * 64 + mf * 16 + lb * 4;
#pragma unroll
    for (int nf = 0; nf < 4; nf++) {
      const int c = n0 + wc * 64 + nf * 16 + la;
      const float bv = bias[c];
#pragma unroll
      for (int rr = 0; rr < 4; rr++) {
        float v = acc[mf][nf][rr] + bv;
        if (RELU) v = fmaxf(v, 0.f);
        Cb[(size_t)(r + rr) * N + c] = f2bf(v);
      }
    }
  }
}

// ---------------- flash attention fwd (32x32 MFMA, permlane exchange) ----------------
__global__ __launch_bounds__(256, 3) void attn_fwd(const u16* __restrict__ Qg,
                                                   const u16* __restrict__ Kg,
                                                   const u16* __restrict__ Vtg,
                                                   u16* __restrict__ Og, int LDM) {
  constexpr int S = 2048, DMO = 1024, NT = S / 64;
  __shared__ u16 Ks[2][64 * 64];
  __shared__ u16 Vt[2][64 * 64];
  const int t = threadIdx.x, w = t >> 6, lane = t & 63;
  const int l5 = lane & 31, hf = lane >> 5;
  const int qb = blockIdx.x, h = blockIdx.y, b = blockIdx.z;
  const size_t base = ((size_t)b * S) * LDM + h * 64;
  const size_t vbase = ((size_t)(b * 16 + h) * 64) * 2048;
  const size_t obase = ((size_t)b * S) * DMO + h * 64;
  const int qrow0 = qb * 128 + w * 32;

#define ATT_STAGE(buf, kt_) { \
  _Pragma("unroll") for (int i = 0; i < 2; i++) { \
    const int s = i * 256 + t; const int r = s >> 3; const int cg = s & 7; \
    gload_lds16(Kg + base + (size_t)((kt_) + r) * LDM + ((cg ^ swz3(r)) << 3), \
                &Ks[buf][s * 8]); } \
  _Pragma("unroll") for (int i = 0; i < 2; i++) { \
    const int s = i * 256 + t; const int r = s >> 3; const int cg = s & 7; \
    gload_lds16(Vtg + vbase + (size_t)r * 2048 + (kt_) + ((cg ^ swz3(r)) << 3), \
                &Vt[buf][s * 8]); } }

  bf16x8 qf[4];
#pragma unroll
  for (int kb = 0; kb < 4; kb++)
    qf[kb] = *(const bf16x8*)&Qg[base + (size_t)(qrow0 + l5) * LDM + kb * 16 + hf * 8];

  f32x16 accO0, accO1, accL;
#pragma unroll
  for (int i = 0; i < 16; i++) { accO0[i] = 0.f; accO1[i] = 0.f; accL[i] = 0.f; }
  float m = -1e30f;

  bf16x8 ones;
#pragma unroll
  for (int i = 0; i < 8; i++) ones[i] = (short)0x3F80;  // bf16 1.0

  ATT_STAGE(0, 0);
  asm volatile("s_waitcnt vmcnt(0)" ::: "memory");
  __builtin_amdgcn_s_barrier();

  for (int kt = 0; kt < NT; ++kt) {
    const int cur = kt & 1;
    if (kt + 1 < NT) ATT_STAGE(cur ^ 1, (kt + 1) * 64);

    f32x16 st0, st1;
#pragma unroll
    for (int i = 0; i < 16; i++) { st0[i] = 0.f; st1[i] = 0.f; }
    __builtin_amdgcn_s_setprio(1);
#pragma unroll
    for (int kb = 0; kb < 4; kb++) {
      const int r0 = l5, r1 = 32 + l5;
      bf16x8 kf0 = *(const bf16x8*)&Ks[cur][r0 * 64 + (((hf + 2 * kb) ^ swz3(r0)) << 3)];
      bf16x8 kf1 = *(const bf16x8*)&Ks[cur][r1 * 64 + (((hf + 2 * kb) ^ swz3(r1)) << 3)];
      st0 = __builtin_amdgcn_mfma_f32_32x32x16_bf16(kf0, qf[kb], st0, 0, 0, 0);
      st1 = __builtin_amdgcn_mfma_f32_32x32x16_bf16(kf1, qf[kb], st1, 0, 0, 0);
    }
    __builtin_amdgcn_s_setprio(0);

    // row max: balanced tree (depth 5) instead of 31-deep serial chain
    float tm[16];
#pragma unroll
    for (int i = 0; i < 8; i++) tm[i] = fmaxf(st0[2 * i], st0[2 * i + 1]);
#pragma unroll
    for (int i = 0; i < 8; i++) tm[8 + i] = fmaxf(st1[2 * i], st1[2 * i + 1]);
#pragma unroll
    for (int i = 0; i < 8; i++) tm[i] = fmaxf(tm[i], tm[i + 8]);
#pragma unroll
    for (int i = 0; i < 4; i++) tm[i] = fmaxf(tm[i], tm[i + 4]);
    tm[0] = fmaxf(tm[0], tm[2]);
    tm[1] = fmaxf(tm[1], tm[3]);
    float rm = fmaxf(tm[0], tm[1]);
    if (__any(rm > m + 8.0f)) {
      float ra = rm, rb = rm;
      asm volatile("v_permlane32_swap_b32 %0, %1" : "+v"(ra), "+v"(rb));
      rm = fmaxf(rm, fmaxf(ra, rb));
      const float mN = fmaxf(m, rm);
      const float al = exp2f(m - mN);
      m = mN;
#pragma unroll
      for (int r = 0; r < 16; r++) {
        const float alr = __shfl(al, (r & 3) + 8 * (r >> 2) + 4 * hf, 64);
        accO0[r] *= alr; accO1[r] *= alr; accL[r] *= alr;
      }
    }

    uint32_t pw0[8], pw1[8];
#pragma unroll
    for (int r2 = 0; r2 < 8; r2++) {
      pw0[r2] = cvtpk(exp2f(st0[2 * r2] - m), exp2f(st0[2 * r2 + 1] - m));
      pw1[r2] = cvtpk(exp2f(st1[2 * r2] - m), exp2f(st1[2 * r2 + 1] - m));
    }
    bf16x8 pf[4];
    {
      uint32_t a0 = pw0[0], b0v = pw0[2], a1 = pw0[1], b1v = pw0[3];
      asm volatile("v_permlane32_swap_b32 %0, %1" : "+v"(a0), "+v"(b0v));
      asm volatile("v_permlane32_swap_b32 %0, %1" : "+v"(a1), "+v"(b1v));
      union { uint32_t u[4]; bf16x8 v; } k;
      k.u[0] = a0; k.u[1] = a1; k.u[2] = b0v; k.u[3] = b1v; pf[0] = k.v;
      uint32_t c0 = pw0[4], d0 = pw0[6], c1 = pw0[5], d1 = pw0[7];
      asm volatile("v_permlane32_swap_b32 %0, %1" : "+v"(c0), "+v"(d0));
      asm volatile("v_permlane32_swap_b32 %0, %1" : "+v"(c1), "+v"(d1));
      k.u[0] = c0; k.u[1] = c1; k.u[2] = d0; k.u[3] = d1; pf[1] = k.v;
      uint32_t e0 = pw1[0], f0 = pw1[2], e1 = pw1[1], f1 = pw1[3];
      asm volatile("v_permlane32_swap_b32 %0, %1" : "+v"(e0), "+v"(f0));
      asm volatile("v_permlane32_swap_b32 %0, %1" : "+v"(e1), "+v"(f1));
      k.u[0] = e0; k.u[1] = e1; k.u[2] = f0; k.u[3] = f1; pf[2] = k.v;
      uint32_t g0 = pw1[4], h0 = pw1[6], g1 = pw1[5], h1 = pw1[7];
      asm volatile("v_permlane32_swap_b32 %0, %1" : "+v"(g0), "+v"(h0));
      asm volatile("v_permlane32_swap_b32 %0, %1" : "+v"(g1), "+v"(h1));
      k.u[0] = g0; k.u[1] = g1; k.u[2] = h0; k.u[3] = h1; pf[3] = k.v;
    }

    __builtin_amdgcn_s_setprio(1);
#pragma unroll
    for (int kb = 0; kb < 4; kb++) {
      const int r0 = l5, r1 = 32 + l5;
      bf16x8 vf0 = *(const bf16x8*)&Vt[cur][r0 * 64 + (((hf + 2 * kb) ^ swz3(r0)) << 3)];
      bf16x8 vf1 = *(const bf16x8*)&Vt[cur][r1 * 64 + (((hf + 2 * kb) ^ swz3(r1)) << 3)];
      accO0 = __builtin_amdgcn_mfma_f32_32x32x16_bf16(pf[kb], vf0, accO0, 0, 0, 0);
      accO1 = __builtin_amdgcn_mfma_f32_32x32x16_bf16(pf[kb], vf1, accO1, 0, 0, 0);
      accL  = __builtin_amdgcn_mfma_f32_32x32x16_bf16(pf[kb], ones, accL, 0, 0, 0);
    }
    __builtin_amdgcn_s_setprio(0);

    asm volatile("s_waitcnt vmcnt(0)" ::: "memory");
    __builtin_amdgcn_s_barrier();
  }
#undef ATT_STAGE

#pragma unroll
  for (int r = 0; r < 16; r++) {
    const float inv = 1.0f / accL[r];
    const int row = qrow0 + (r & 3) + 8 * (r >> 2) + 4 * hf;
    Og[obase + (size_t)row * DMO + l5]      = f2bf_ru(accO0[r] * inv);
    Og[obase + (size_t)row * DMO + 32 + l5] = f2bf_ru(accO1[r] * inv);
  }
}

// ---------------- fused residual-add + LayerNorm (D=1024) ----------------
template <int AF32, int OUTF32>
__global__ __launch_bounds__(256) void add_ln(const void* __restrict__ Ap,
                                              const u16* __restrict__ Bb,
                                              const float* __restrict__ g,
                                              const float* __restrict__ be,
                                              void* __restrict__ Yp) {
  constexpr int D = 1024;
  const int row = blockIdx.x, t = threadIdx.x;
  f32x4 a;
  if (AF32) {
    a = ((const f32x4*)((const float*)Ap + (size_t)row * D))[t];
  } else {
    u16x4 av = ((const u16x4*)((const u16*)Ap + (size_t)row * D))[t];
#pragma unroll
    for (int i = 0; i < 4; i++) a[i] = bf2f(av[i]);
  }
  u16x4 bv16 = ((const u16x4*)(Bb + (size_t)row * D))[t];
  f32x4 x;
#pragma unroll
  for (int i = 0; i < 4; i++) x[i] = a[i] + bf2f(bv16[i]);
  float s1 = x[0] + x[1] + x[2] + x[3];
  float s2 = x[0] * x[0] + x[1] * x[1] + x[2] * x[2] + x[3] * x[3];
#pragma unroll
  for (int off = 32; off > 0; off >>= 1) {
    s1 += __shfl_down(s1, off, 64);
    s2 += __shfl_down(s2, off, 64);
  }
  __shared__ float sm[8];
  const int w = t >> 6, lane = t & 63;
  if (lane == 0) { sm[w] = s1; sm[4 + w] = s2; }
  __syncthreads();
  s1 = sm[0] + sm[1] + sm[2] + sm[3];
  s2 = sm[4] + sm[5] + sm[6] + sm[7];
  const float mean = s1 * (1.0f / D);
  const float var = s2 * (1.0f / D) - mean * mean;
  const float rstd = rsqrtf(var + 1e-5f);
  const f32x4 gv = ((const f32x4*)g)[t];
  const f32x4 bv = ((const f32x4*)be)[t];
  f32x4 y;
#pragma unroll
  for (int i = 0; i < 4; i++) y[i] = (x[i] - mean) * rstd * gv[i] + bv[i];
  if (OUTF32) {
    ((f32x4*)((float*)Yp + (size_t)row * D))[t] = y;
  } else {
    u16x4 o;
#pragma unroll
    for (int i = 0; i < 4; i++) o[i] = f2bf(y[i]);
    ((u16x4*)((u16*)Yp + (size_t)row * D))[t] = o;
  }
}

extern "C" void kernel_launch(void* const* d_in, const int* in_sizes, int n_in,
                              void* d_out, int out_size, void* d_ws, size_t ws_size,
                              hipStream_t stream) {
  const float* X   = (const float*)d_in[0];
  const float* Wq  = (const float*)d_in[1];
  const float* bq  = (const float*)d_in[2];
  const float* Wk  = (const float*)d_in[3];
  const float* bk  = (const float*)d_in[4];
  const float* Wv  = (const float*)d_in[5];
  const float* bv  = (const float*)d_in[6];
  const float* Wo  = (const float*)d_in[7];
  const float* bo  = (const float*)d_in[8];
  const float* g1  = (const float*)d_in[9];
  const float* be1 = (const float*)d_in[10];
  const float* W1  = (const float*)d_in[11];
  const float* b1  = (const float*)d_in[12];
  const float* W2  = (const float*)d_in[13];
  const float* b2  = (const float*)d_in[14];
  const float* g2  = (const float*)d_in[15];
  const float* be2 = (const float*)d_in[16];

  // ---- workspace plan (peak 120 MB, lifetime-aliased) ----
  const size_t MB = 1ull << 20;
  char* wsb = (char*)d_ws;
  u16*   WqkvT = (u16*)(wsb + 0 * MB);
  u16*   WoT   = (u16*)(wsb + 6 * MB);
  u16*   W1T   = (u16*)(wsb + 8 * MB);
  u16*   W2T   = (u16*)(wsb + 16 * MB);
  u16*   Xb    = (u16*)(wsb + 24 * MB);
  u16*   Ab    = (u16*)(wsb + 24 * MB);
  u16*   Fb    = (u16*)(wsb + 24 * MB);
  u16*   QKVb  = (u16*)(wsb + 40 * MB);
  u16*   Hb    = (u16*)(wsb + 40 * MB);
  float* bqkv  = (float*)(wsb + 88 * MB);
  u16*   Cx    = (u16*)(wsb + 88 * MB);
  u16*   Vt_g  = (u16*)(wsb + 104 * MB);
  u16*   Yb    = (u16*)(wsb + 104 * MB);
  (void)ws_size; (void)in_sizes; (void)n_in; (void)out_size;

  cast_bf16<<<2048, 256, 0, stream>>>(X, Xb, 8192 * 1024 / 8);
  concat3<<<12, 256, 0, stream>>>(bq, bk, bv, bqkv);
  transpose_cast<<<dim3(32, 32), 256, 0, stream>>>(Wq, WqkvT, 1024, 1024, QSCALE);
  transpose_cast<<<dim3(32, 32), 256, 0, stream>>>(Wk, WqkvT + 1024 * 1024, 1024, 1024, 1.0f);
  transpose_cast<<<dim3(32, 32), 256, 0, stream>>>(Wv, WqkvT + 2 * 1024 * 1024, 1024, 1024, 1.0f);
  transpose_cast<<<dim3(32, 32), 256, 0, stream>>>(Wo, WoT, 1024, 1024, 1.0f);
  transpose_cast<<<dim3(128, 32), 256, 0, stream>>>(W1, W1T, 1024, 4096, 1.0f);
  transpose_cast<<<dim3(32, 128), 256, 0, stream>>>(W2, W2T, 4096, 1024, 1.0f);

  // fused QKV projection (Q pre-scaled): [8192,1024] @ [1024,3072]
  gemm8p<0><<<384, 512, 0, stream>>>(Xb, WqkvT, bqkv, QKVb, 8192, 3072, 1024, 12);

  vtrans<<<dim3(32, 16, 4), 256, 0, stream>>>(QKVb, Vt_g);
  attn_fwd<<<dim3(16, 16, 4), 256, 0, stream>>>(QKVb, QKVb + 1024, Vt_g, Cx, 3072);

  gemm8n<0><<<256, 512, 0, stream>>>(Cx, WoT, bo, Ab, 8192, 1024, 1024, 4);
  add_ln<1, 0><<<8192, 256, 0, stream>>>(X, Ab, g1, be1, Yb);
  gemm8p<1><<<512, 512, 0, stream>>>(Yb, W1T, b1, Hb, 8192, 4096, 1024, 16);
  gemm8n<0><<<256, 512, 0, stream>>>(Hb, W2T, b2, Fb, 8192, 1024, 4096, 4);
  add_ln<0, 1><<<8192, 256, 0, stream>>>(Yb, Fb, g2, be2, d_out);
}

// Round 18
// 415.347 us; speedup vs baseline: 1.0404x; 1.0404x over previous
//
#include <hip/hip_runtime.h>
#include <stdint.h>

typedef unsigned short u16;
typedef short bf16x8 __attribute__((ext_vector_type(8)));
typedef float f32x4 __attribute__((ext_vector_type(4)));
typedef float f32x16 __attribute__((ext_vector_type(16)));
typedef u16 u16x4 __attribute__((ext_vector_type(4)));
typedef u16 u16x8 __attribute__((ext_vector_type(8)));

#define LOG2E 1.4426950408889634f
#define QSCALE (0.125f * LOG2E)

__device__ __forceinline__ u16 f2bf(float f) {
  union { float f; uint32_t u; } x; x.f = f;
  uint32_t r = x.u + 0x7fffu + ((x.u >> 16) & 1u);
  return (u16)(r >> 16);
}
__device__ __forceinline__ u16 f2bf_ru(float f) {
  union { float f; uint32_t u; } x; x.f = f;
  return (u16)((x.u + 0x8000u) >> 16);
}
__device__ __forceinline__ float bf2f(u16 h) {
  union { uint32_t u; float f; } x; x.u = ((uint32_t)h) << 16;
  return x.f;
}
__device__ __forceinline__ uint32_t cvtpk(float lo, float hi) {
  uint32_t r;
  asm("v_cvt_pk_bf16_f32 %0, %1, %2" : "=v"(r) : "v"(lo), "v"(hi));
  return r;
}
// 16B-granule XOR swizzle (involution, low 3 bits of granule index)
__device__ __forceinline__ int swz3(int row) { return (row ^ (row >> 3)) & 7; }

__device__ __forceinline__ void gload_lds16(const void* g, void* lds) {
  __builtin_amdgcn_global_load_lds(
      (const __attribute__((address_space(1))) void*)g,
      (__attribute__((address_space(3))) void*)lds, 16, 0, 0);
}

// ---------------- cast f32 -> bf16 (8 elems/thread) ----------------
__global__ __launch_bounds__(256) void cast_bf16(const float* __restrict__ in,
                                                 u16* __restrict__ out, int n8) {
  int i = blockIdx.x * 256 + threadIdx.x;
  const int stride = gridDim.x * 256;
  for (; i < n8; i += stride) {
    const f32x4* p = (const f32x4*)in + (size_t)i * 2;
    f32x4 a = p[0], b = p[1];
    u16x8 o;
    o[0] = f2bf(a[0]); o[1] = f2bf(a[1]); o[2] = f2bf(a[2]); o[3] = f2bf(a[3]);
    o[4] = f2bf(b[0]); o[5] = f2bf(b[1]); o[6] = f2bf(b[2]); o[7] = f2bf(b[3]);
    ((u16x8*)out)[i] = o;
  }
}

// ---------------- concat 3 bias vectors; bq pre-scaled by QSCALE ----------------
__global__ __launch_bounds__(256) void concat3(const float* __restrict__ a,
                                               const float* __restrict__ b,
                                               const float* __restrict__ c,
                                               float* __restrict__ o) {
  int i = blockIdx.x * 256 + threadIdx.x;
  if (i < 3072)
    o[i] = i < 1024 ? a[i] * QSCALE : (i < 2048 ? b[i - 1024] : c[i - 2048]);
}

// ---------------- transpose + cast + scale: W[R][C] f32 -> WT[C][R] bf16 ----------------
__global__ __launch_bounds__(256) void transpose_cast(const float* __restrict__ in,
                                                      u16* __restrict__ out, int R, int C,
                                                      float scale) {
  __shared__ float tile[32][33];
  const int bc = blockIdx.x * 32, br = blockIdx.y * 32;
  const int tx = threadIdx.x & 31, ty = threadIdx.x >> 5;  // 32 x 8
#pragma unroll
  for (int i = 0; i < 32; i += 8)
    tile[ty + i][tx] = in[(size_t)(br + ty + i) * C + bc + tx];
  __syncthreads();
#pragma unroll
  for (int i = 0; i < 32; i += 8)
    out[(size_t)(bc + ty + i) * R + br + tx] = f2bf(tile[tx][ty + i] * scale);
}

// ---------------- V transpose: QKV V-part [s][dh] -> Vt_g[b*16+h][dh][S] ----------------
__global__ __launch_bounds__(256) void vtrans(const u16* __restrict__ QKV,
                                              u16* __restrict__ Vtg) {
  __shared__ u16 tl[64][65];
  const int t = threadIdx.x;
  const int sblk = blockIdx.x, h = blockIdx.y, b = blockIdx.z;
  const int s0 = sblk * 64;
  const size_t ibase = ((size_t)b * 2048) * 3072 + 2048 + h * 64;
#pragma unroll
  for (int i = 0; i < 2; i++) {
    const int idx = i * 256 + t;
    const int sl = idx >> 3, d0 = (idx & 7) * 8;
    bf16x8 v = *(const bf16x8*)&QKV[ibase + (size_t)(s0 + sl) * 3072 + d0];
#pragma unroll
    for (int e = 0; e < 8; e++) tl[d0 + e][sl] = (u16)v[e];
  }
  __syncthreads();
  const size_t ob = ((size_t)(b * 16 + h) * 64) * 2048;
#pragma unroll
  for (int i = 0; i < 2; i++) {
    const int idx = i * 256 + t;
    const int r = idx >> 3, c0 = (idx & 7) * 8;
    u16x8 o;
#pragma unroll
    for (int e = 0; e < 8; e++) o[e] = tl[r][c0 + e];
    *(u16x8*)&Vtg[ob + (size_t)r * 2048 + s0 + c0] = o;
  }
}

// ---------------- GEMM 256x256, 4-phase + counted vmcnt, 32x32 MFMA ----------------
template <int RELU>
__global__ __launch_bounds__(512, 2) void gemm8p(const u16* __restrict__ A,
                                                 const u16* __restrict__ BT,
                                                 const float* __restrict__ bias,
                                                 u16* __restrict__ Cb,
                                                 int M, int N, int K, int nbx) {
  __shared__ u16 As[2][256 * 64];
  __shared__ u16 Bs[2][256 * 64];
  const int t = threadIdx.x;
  const int w = t >> 6, lane = t & 63;
  const int l5 = lane & 31, hf = lane >> 5;
  const int wr = w >> 2, wc = w & 3;
  int bid = (int)blockIdx.x;
  const int cpx = (int)gridDim.x >> 3;
  bid = (bid & 7) * cpx + (bid >> 3);
  const int m0 = (bid / nbx) * 256, n0 = (bid % nbx) * 256;
  const int NT = K >> 6;
  const int row64 = t >> 3;
  const int colp = ((t & 7) ^ swz3(row64)) << 3;

#define STG_A(buf, tile, q) \
  gload_lds16(A + (size_t)(m0 + (q)*64 + row64) * K + ((tile) << 6) + colp, \
              &As[buf][(q)*4096 + w * 512])
#define STG_B(buf, tile, q) \
  gload_lds16(BT + (size_t)(n0 + (q)*64 + row64) * K + ((tile) << 6) + colp, \
              &Bs[buf][(q)*4096 + w * 512])
#define LDA32(dst, mfi, kb) { const int r_ = wr * 128 + (mfi)*32 + l5; \
  dst = *(const bf16x8*)&As[cur][r_ * 64 + (((((kb) << 1) + hf) ^ swz3(r_)) << 3)]; }
#define LDB32(dst, nfi, kb) { const int r_ = wc * 64 + (nfi)*32 + l5; \
  dst = *(const bf16x8*)&Bs[cur][r_ * 64 + (((((kb) << 1) + hf) ^ swz3(r_)) << 3)]; }
#define MFMA32(mh, nfi, barr) \
  __builtin_amdgcn_s_setprio(1); \
  _Pragma("unroll") for (int kb = 0; kb < 4; kb++) \
  _Pragma("unroll") for (int i = 0; i < 2; i++) \
    acc[((mh)*2 + i) * 2 + (nfi)] = __builtin_amdgcn_mfma_f32_32x32x16_bf16( \
        af[i][kb], barr[kb], acc[((mh)*2 + i) * 2 + (nfi)], 0, 0, 0); \
  __builtin_amdgcn_s_setprio(0);
#define BAR1() __builtin_amdgcn_s_barrier(); \
  asm volatile("s_waitcnt lgkmcnt(0)" ::: "memory"); \
  __builtin_amdgcn_sched_barrier(0)

  f32x16 acc[8];
#pragma unroll
  for (int i = 0; i < 8; i++)
#pragma unroll
    for (int j = 0; j < 16; j++) acc[i][j] = 0.f;

  STG_A(0, 0, 0); STG_A(0, 0, 2);
  STG_B(0, 0, 0); STG_B(0, 0, 1); STG_B(0, 0, 2); STG_B(0, 0, 3);
  STG_A(0, 0, 1); STG_A(0, 0, 3);
  asm volatile("s_waitcnt vmcnt(2)" ::: "memory");
  __builtin_amdgcn_s_barrier();

  for (int tile = 0; tile < NT; ++tile) {
    const int cur = tile & 1, nxt = cur ^ 1;
    const bool hn = (tile + 1) < NT;
    bf16x8 af[2][4], b0[4], b1[4];
#pragma unroll
    for (int kb = 0; kb < 4; kb++) { LDA32(af[0][kb], 0, kb); LDA32(af[1][kb], 1, kb); }
#pragma unroll
    for (int kb = 0; kb < 4; kb++) { LDB32(b0[kb], 0, kb); }
    if (hn) { STG_A(nxt, tile + 1, 0); STG_A(nxt, tile + 1, 2); }
    BAR1();
    MFMA32(0, 0, b0);
    __builtin_amdgcn_s_barrier();
#pragma unroll
    for (int kb = 0; kb < 4; kb++) { LDB32(b1[kb], 1, kb); }
    if (hn) { STG_B(nxt, tile + 1, 0); STG_B(nxt, tile + 1, 1); }
    BAR1();
    MFMA32(0, 1, b1);
    if (hn) { asm volatile("s_waitcnt vmcnt(4)" ::: "memory"); }
    else    { asm volatile("s_waitcnt vmcnt(0)" ::: "memory"); }
    __builtin_amdgcn_s_barrier();
#pragma unroll
    for (int kb = 0; kb < 4; kb++) { LDA32(af[0][kb], 2, kb); LDA32(af[1][kb], 3, kb); }
    if (hn) { STG_B(nxt, tile + 1, 2); STG_B(nxt, tile + 1, 3); }
    BAR1();
    MFMA32(1, 0, b0);
    __builtin_amdgcn_s_barrier();
    if (hn) { STG_A(nxt, tile + 1, 1); STG_A(nxt, tile + 1, 3); }
    BAR1();
    MFMA32(1, 1, b1);
    if (hn) { asm volatile("s_waitcnt vmcnt(2)" ::: "memory"); }
    __builtin_amdgcn_s_barrier();
  }
#undef STG_A
#undef STG_B
#undef LDA32
#undef LDB32
#undef MFMA32
#undef BAR1

#pragma unroll
  for (int mf = 0; mf < 4; mf++) {
#pragma unroll
    for (int nf = 0; nf < 2; nf++) {
      const int c = n0 + wc * 64 + nf * 32 + l5;
      const float bv = bias[c];
#pragma unroll
      for (int reg = 0; reg < 16; reg++) {
        const int r = m0 + wr * 128 + mf * 32 + (reg & 3) + 8 * (reg >> 2) + 4 * hf;
        float v = acc[mf * 2 + nf][reg] + bv;
        if (RELU) v = fmaxf(v, 0.f);
        Cb[(size_t)r * N + c] = f2bf(v);
      }
    }
  }
}

// ---------------- GEMM 128x256, 2-phase + counted vmcnt, 32x32 MFMA ----------------
// 8 waves (2M x 4N), per-wave 64x64 = 2x2 frags of 32x32. Per K-tile:
// 8 A + 8 B ds_read_b128 (was 24 with 16x16), 16 mfma_32x32x16 (128 cyc
// vs 160). Staging order + vmcnt(3)/vmcnt(2) accounting unchanged from
// the verified round-11 schedule.
template <int RELU>
__global__ __launch_bounds__(512, 2) void gemm8n(const u16* __restrict__ A,
                                                 const u16* __restrict__ BT,
                                                 const float* __restrict__ bias,
                                                 u16* __restrict__ Cb,
                                                 int M, int N, int K, int nbx) {
  __shared__ u16 As[2][128 * 64];
  __shared__ u16 Bs[2][256 * 64];
  const int t = threadIdx.x;
  const int w = t >> 6, lane = t & 63;
  const int l5 = lane & 31, hf = lane >> 5;
  const int wr = w >> 2, wc = w & 3;
  int bid = (int)blockIdx.x;
  const int cpx = (int)gridDim.x >> 3;
  bid = (bid & 7) * cpx + (bid >> 3);
  const int m0 = (bid / nbx) * 128, n0 = (bid % nbx) * 256;
  const int NT = K >> 6;
  const int rowA = t >> 3;
  const int colpA = ((t & 7) ^ swz3(rowA)) << 3;

#define STG_An(buf, tile, q) \
  gload_lds16(A + (size_t)(m0 + (q)*64 + rowA) * K + ((tile) << 6) + colpA, \
              &As[buf][(q)*4096 + t * 8])
#define STG_Bn(buf, tile, c, i) { \
  const int r32_ = (i)*64 + (t >> 3); \
  const int R_ = ((r32_ >> 5) << 6) + (c)*32 + (r32_ & 31); \
  const int cp_ = ((t & 7) ^ swz3(R_)) << 3; \
  gload_lds16(BT + (size_t)(n0 + R_) * K + ((tile) << 6) + cp_, \
              &Bs[buf][R_ * 64 + (t & 7) * 8]); }
#define LDAn(dst, mfi, kb) { const int r_ = wr * 64 + (mfi)*32 + l5; \
  dst = *(const bf16x8*)&As[cur][r_ * 64 + (((((kb) << 1) + hf) ^ swz3(r_)) << 3)]; }
#define LDBn(dst, nfi, kb) { const int r_ = wc * 64 + (nfi)*32 + l5; \
  dst = *(const bf16x8*)&Bs[cur][r_ * 64 + (((((kb) << 1) + hf) ^ swz3(r_)) << 3)]; }
#define MFMAn(nfi, barr) \
  __builtin_amdgcn_s_setprio(1); \
  _Pragma("unroll") for (int kb = 0; kb < 4; kb++) \
  _Pragma("unroll") for (int i = 0; i < 2; i++) \
    acc[i * 2 + (nfi)] = __builtin_amdgcn_mfma_f32_32x32x16_bf16( \
        af[i][kb], barr[kb], acc[i * 2 + (nfi)], 0, 0, 0); \
  __builtin_amdgcn_s_setprio(0);
#define BARn() __builtin_amdgcn_s_barrier(); \
  asm volatile("s_waitcnt lgkmcnt(0)" ::: "memory"); \
  __builtin_amdgcn_sched_barrier(0)

  f32x16 acc[4];  // mf*2 + nf, static indices only
#pragma unroll
  for (int i = 0; i < 4; i++)
#pragma unroll
    for (int j = 0; j < 16; j++) acc[i][j] = 0.f;

  STG_Bn(0, 0, 0, 0); STG_Bn(0, 0, 0, 1); STG_An(0, 0, 0);
  STG_An(0, 0, 1); STG_Bn(0, 0, 1, 0); STG_Bn(0, 0, 1, 1);
  asm volatile("s_waitcnt vmcnt(0)" ::: "memory");
  __builtin_amdgcn_s_barrier();

  for (int tile = 0; tile < NT; ++tile) {
    const int cur = tile & 1, nxt = cur ^ 1;
    const bool hn = (tile + 1) < NT;
    bf16x8 af[2][4], b0[4], b1[4];
    // ---- phase 0: nf0 — load af(mf0-1) + b0 ----
#pragma unroll
    for (int kb = 0; kb < 4; kb++) { LDAn(af[0][kb], 0, kb); LDAn(af[1][kb], 1, kb); }
#pragma unroll
    for (int kb = 0; kb < 4; kb++) { LDBn(b0[kb], 0, kb); }
    if (hn) { STG_Bn(nxt, tile + 1, 0, 0); STG_Bn(nxt, tile + 1, 0, 1); STG_An(nxt, tile + 1, 0); }
    BARn();
    MFMAn(0, b0);
    if (hn) { asm volatile("s_waitcnt vmcnt(3)" ::: "memory"); }
    else    { asm volatile("s_waitcnt vmcnt(0)" ::: "memory"); }
    __builtin_amdgcn_s_barrier();
    // ---- phase 1: nf1 — load b1; af reused from regs ----
#pragma unroll
    for (int kb = 0; kb < 4; kb++) { LDBn(b1[kb], 1, kb); }
    if (hn) { STG_An(nxt, tile + 1, 1); STG_Bn(nxt, tile + 1, 1, 0); STG_Bn(nxt, tile + 1, 1, 1); }
    BARn();
    MFMAn(1, b1);
    if (hn) { asm volatile("s_waitcnt vmcnt(2)" ::: "memory"); }
    __builtin_amdgcn_s_barrier();
  }
#undef STG_An
#undef STG_Bn
#undef LDAn
#undef LDBn
#undef MFMAn
#undef BARn

  // epilogue: col = n0+wc*64+nf*32+l5, row = m0+wr*64+mf*32+(reg&3)+8(reg>>2)+4hf
#pragma unroll
  for (int mf = 0; mf < 2; mf++) {
#pragma unroll
    for (int nf = 0; nf < 2; nf++) {
      const int c = n0 + wc * 64 + nf * 32 + l5;
      const float bv = bias[c];
#pragma unroll
      for (int reg = 0; reg < 16; reg++) {
        const int r = m0 + wr * 64 + mf * 32 + (reg & 3) + 8 * (reg >> 2) + 4 * hf;
        float v = acc[mf * 2 + nf][reg] + bv;
        if (RELU) v = fmaxf(v, 0.f);
        Cb[(size_t)r * N + c] = f2bf(v);
      }
    }
  }
}

// ---------------- flash attention fwd (32x32 MFMA, permlane exchange) ----------------
// Row-max is a SERIAL fmax chain on purpose: the balanced-tree variant
// measured 5 us SLOWER (round 17) — attn is VALU-throughput-bound and the
// compiler already interleaves the chain with independent work.
__global__ __launch_bounds__(256, 3) void attn_fwd(const u16* __restrict__ Qg,
                                                   const u16* __restrict__ Kg,
                                                   const u16* __restrict__ Vtg,
                                                   u16* __restrict__ Og, int LDM) {
  constexpr int S = 2048, DMO = 1024, NT = S / 64;
  __shared__ u16 Ks[2][64 * 64];
  __shared__ u16 Vt[2][64 * 64];
  const int t = threadIdx.x, w = t >> 6, lane = t & 63;
  const int l5 = lane & 31, hf = lane >> 5;
  const int qb = blockIdx.x, h = blockIdx.y, b = blockIdx.z;
  const size_t base = ((size_t)b * S) * LDM + h * 64;
  const size_t vbase = ((size_t)(b * 16 + h) * 64) * 2048;
  const size_t obase = ((size_t)b * S) * DMO + h * 64;
  const int qrow0 = qb * 128 + w * 32;

#define ATT_STAGE(buf, kt_) { \
  _Pragma("unroll") for (int i = 0; i < 2; i++) { \
    const int s = i * 256 + t; const int r = s >> 3; const int cg = s & 7; \
    gload_lds16(Kg + base + (size_t)((kt_) + r) * LDM + ((cg ^ swz3(r)) << 3), \
                &Ks[buf][s * 8]); } \
  _Pragma("unroll") for (int i = 0; i < 2; i++) { \
    const int s = i * 256 + t; const int r = s >> 3; const int cg = s & 7; \
    gload_lds16(Vtg + vbase + (size_t)r * 2048 + (kt_) + ((cg ^ swz3(r)) << 3), \
                &Vt[buf][s * 8]); } }

  bf16x8 qf[4];
#pragma unroll
  for (int kb = 0; kb < 4; kb++)
    qf[kb] = *(const bf16x8*)&Qg[base + (size_t)(qrow0 + l5) * LDM + kb * 16 + hf * 8];

  f32x16 accO0, accO1, accL;
#pragma unroll
  for (int i = 0; i < 16; i++) { accO0[i] = 0.f; accO1[i] = 0.f; accL[i] = 0.f; }
  float m = -1e30f;

  bf16x8 ones;
#pragma unroll
  for (int i = 0; i < 8; i++) ones[i] = (short)0x3F80;  // bf16 1.0

  ATT_STAGE(0, 0);
  asm volatile("s_waitcnt vmcnt(0)" ::: "memory");
  __builtin_amdgcn_s_barrier();

  for (int kt = 0; kt < NT; ++kt) {
    const int cur = kt & 1;
    if (kt + 1 < NT) ATT_STAGE(cur ^ 1, (kt + 1) * 64);

    f32x16 st0, st1;
#pragma unroll
    for (int i = 0; i < 16; i++) { st0[i] = 0.f; st1[i] = 0.f; }
    __builtin_amdgcn_s_setprio(1);
#pragma unroll
    for (int kb = 0; kb < 4; kb++) {
      const int r0 = l5, r1 = 32 + l5;
      bf16x8 kf0 = *(const bf16x8*)&Ks[cur][r0 * 64 + (((hf + 2 * kb) ^ swz3(r0)) << 3)];
      bf16x8 kf1 = *(const bf16x8*)&Ks[cur][r1 * 64 + (((hf + 2 * kb) ^ swz3(r1)) << 3)];
      st0 = __builtin_amdgcn_mfma_f32_32x32x16_bf16(kf0, qf[kb], st0, 0, 0, 0);
      st1 = __builtin_amdgcn_mfma_f32_32x32x16_bf16(kf1, qf[kb], st1, 0, 0, 0);
    }
    __builtin_amdgcn_s_setprio(0);

    // row max: serial chain (measured faster than tree, round 17)
    float rm = st0[0];
#pragma unroll
    for (int i = 1; i < 16; i++) rm = fmaxf(rm, st0[i]);
#pragma unroll
    for (int i = 0; i < 16; i++) rm = fmaxf(rm, st1[i]);
    if (__any(rm > m + 8.0f)) {  // defer-max THR=8 (log2 units)
      float ra = rm, rb = rm;
      asm volatile("v_permlane32_swap_b32 %0, %1" : "+v"(ra), "+v"(rb));
      rm = fmaxf(rm, fmaxf(ra, rb));
      const float mN = fmaxf(m, rm);
      const float al = exp2f(m - mN);
      m = mN;
#pragma unroll
      for (int r = 0; r < 16; r++) {
        const float alr = __shfl(al, (r & 3) + 8 * (r >> 2) + 4 * hf, 64);
        accO0[r] *= alr; accO1[r] *= alr; accL[r] *= alr;
      }
    }

    uint32_t pw0[8], pw1[8];
#pragma unroll
    for (int r2 = 0; r2 < 8; r2++) {
      pw0[r2] = cvtpk(exp2f(st0[2 * r2] - m), exp2f(st0[2 * r2 + 1] - m));
      pw1[r2] = cvtpk(exp2f(st1[2 * r2] - m), exp2f(st1[2 * r2 + 1] - m));
    }
    bf16x8 pf[4];
    {
      uint32_t a0 = pw0[0], b0v = pw0[2], a1 = pw0[1], b1v = pw0[3];
      asm volatile("v_permlane32_swap_b32 %0, %1" : "+v"(a0), "+v"(b0v));
      asm volatile("v_permlane32_swap_b32 %0, %1" : "+v"(a1), "+v"(b1v));
      union { uint32_t u[4]; bf16x8 v; } k;
      k.u[0] = a0; k.u[1] = a1; k.u[2] = b0v; k.u[3] = b1v; pf[0] = k.v;
      uint32_t c0 = pw0[4], d0 = pw0[6], c1 = pw0[5], d1 = pw0[7];
      asm volatile("v_permlane32_swap_b32 %0, %1" : "+v"(c0), "+v"(d0));
      asm volatile("v_permlane32_swap_b32 %0, %1" : "+v"(c1), "+v"(d1));
      k.u[0] = c0; k.u[1] = c1; k.u[2] = d0; k.u[3] = d1; pf[1] = k.v;
      uint32_t e0 = pw1[0], f0 = pw1[2], e1 = pw1[1], f1 = pw1[3];
      asm volatile("v_permlane32_swap_b32 %0, %1" : "+v"(e0), "+v"(f0));
      asm volatile("v_permlane32_swap_b32 %0, %1" : "+v"(e1), "+v"(f1));
      k.u[0] = e0; k.u[1] = e1; k.u[2] = f0; k.u[3] = f1; pf[2] = k.v;
      uint32_t g0 = pw1[4], h0 = pw1[6], g1 = pw1[5], h1 = pw1[7];
      asm volatile("v_permlane32_swap_b32 %0, %1" : "+v"(g0), "+v"(h0));
      asm volatile("v_permlane32_swap_b32 %0, %1" : "+v"(g1), "+v"(h1));
      k.u[0] = g0; k.u[1] = g1; k.u[2] = h0; k.u[3] = h1; pf[3] = k.v;
    }

    __builtin_amdgcn_s_setprio(1);
#pragma unroll
    for (int kb = 0; kb < 4; kb++) {
      const int r0 = l5, r1 = 32 + l5;
      bf16x8 vf0 = *(const bf16x8*)&Vt[cur][r0 * 64 + (((hf + 2 * kb) ^ swz3(r0)) << 3)];
      bf16x8 vf1 = *(const bf16x8*)&Vt[cur][r1 * 64 + (((hf + 2 * kb) ^ swz3(r1)) << 3)];
      accO0 = __builtin_amdgcn_mfma_f32_32x32x16_bf16(pf[kb], vf0, accO0, 0, 0, 0);
      accO1 = __builtin_amdgcn_mfma_f32_32x32x16_bf16(pf[kb], vf1, accO1, 0, 0, 0);
      accL  = __builtin_amdgcn_mfma_f32_32x32x16_bf16(pf[kb], ones, accL, 0, 0, 0);
    }
    __builtin_amdgcn_s_setprio(0);

    asm volatile("s_waitcnt vmcnt(0)" ::: "memory");
    __builtin_amdgcn_s_barrier();
  }
#undef ATT_STAGE

#pragma unroll
  for (int r = 0; r < 16; r++) {
    const float inv = 1.0f / accL[r];
    const int row = qrow0 + (r & 3) + 8 * (r >> 2) + 4 * hf;
    Og[obase + (size_t)row * DMO + l5]      = f2bf_ru(accO0[r] * inv);
    Og[obase + (size_t)row * DMO + 32 + l5] = f2bf_ru(accO1[r] * inv);
  }
}

// ---------------- fused residual-add + LayerNorm (D=1024) ----------------
template <int AF32, int OUTF32>
__global__ __launch_bounds__(256) void add_ln(const void* __restrict__ Ap,
                                              const u16* __restrict__ Bb,
                                              const float* __restrict__ g,
                                              const float* __restrict__ be,
                                              void* __restrict__ Yp) {
  constexpr int D = 1024;
  const int row = blockIdx.x, t = threadIdx.x;
  f32x4 a;
  if (AF32) {
    a = ((const f32x4*)((const float*)Ap + (size_t)row * D))[t];
  } else {
    u16x4 av = ((const u16x4*)((const u16*)Ap + (size_t)row * D))[t];
#pragma unroll
    for (int i = 0; i < 4; i++) a[i] = bf2f(av[i]);
  }
  u16x4 bv16 = ((const u16x4*)(Bb + (size_t)row * D))[t];
  f32x4 x;
#pragma unroll
  for (int i = 0; i < 4; i++) x[i] = a[i] + bf2f(bv16[i]);
  float s1 = x[0] + x[1] + x[2] + x[3];
  float s2 = x[0] * x[0] + x[1] * x[1] + x[2] * x[2] + x[3] * x[3];
#pragma unroll
  for (int off = 32; off > 0; off >>= 1) {
    s1 += __shfl_down(s1, off, 64);
    s2 += __shfl_down(s2, off, 64);
  }
  __shared__ float sm[8];
  const int w = t >> 6, lane = t & 63;
  if (lane == 0) { sm[w] = s1; sm[4 + w] = s2; }
  __syncthreads();
  s1 = sm[0] + sm[1] + sm[2] + sm[3];
  s2 = sm[4] + sm[5] + sm[6] + sm[7];
  const float mean = s1 * (1.0f / D);
  const float var = s2 * (1.0f / D) - mean * mean;
  const float rstd = rsqrtf(var + 1e-5f);
  const f32x4 gv = ((const f32x4*)g)[t];
  const f32x4 bv = ((const f32x4*)be)[t];
  f32x4 y;
#pragma unroll
  for (int i = 0; i < 4; i++) y[i] = (x[i] - mean) * rstd * gv[i] + bv[i];
  if (OUTF32) {
    ((f32x4*)((float*)Yp + (size_t)row * D))[t] = y;
  } else {
    u16x4 o;
#pragma unroll
    for (int i = 0; i < 4; i++) o[i] = f2bf(y[i]);
    ((u16x4*)((u16*)Yp + (size_t)row * D))[t] = o;
  }
}

extern "C" void kernel_launch(void* const* d_in, const int* in_sizes, int n_in,
                              void* d_out, int out_size, void* d_ws, size_t ws_size,
                              hipStream_t stream) {
  const float* X   = (const float*)d_in[0];
  const float* Wq  = (const float*)d_in[1];
  const float* bq  = (const float*)d_in[2];
  const float* Wk  = (const float*)d_in[3];
  const float* bk  = (const float*)d_in[4];
  const float* Wv  = (const float*)d_in[5];
  const float* bv  = (const float*)d_in[6];
  const float* Wo  = (const float*)d_in[7];
  const float* bo  = (const float*)d_in[8];
  const float* g1  = (const float*)d_in[9];
  const float* be1 = (const float*)d_in[10];
  const float* W1  = (const float*)d_in[11];
  const float* b1  = (const float*)d_in[12];
  const float* W2  = (const float*)d_in[13];
  const float* b2  = (const float*)d_in[14];
  const float* g2  = (const float*)d_in[15];
  const float* be2 = (const float*)d_in[16];

  // ---- workspace plan (peak 120 MB, lifetime-aliased) ----
  const size_t MB = 1ull << 20;
  char* wsb = (char*)d_ws;
  u16*   WqkvT = (u16*)(wsb + 0 * MB);
  u16*   WoT   = (u16*)(wsb + 6 * MB);
  u16*   W1T   = (u16*)(wsb + 8 * MB);
  u16*   W2T   = (u16*)(wsb + 16 * MB);
  u16*   Xb    = (u16*)(wsb + 24 * MB);
  u16*   Ab    = (u16*)(wsb + 24 * MB);
  u16*   Fb    = (u16*)(wsb + 24 * MB);
  u16*   QKVb  = (u16*)(wsb + 40 * MB);
  u16*   Hb    = (u16*)(wsb + 40 * MB);
  float* bqkv  = (float*)(wsb + 88 * MB);
  u16*   Cx    = (u16*)(wsb + 88 * MB);
  u16*   Vt_g  = (u16*)(wsb + 104 * MB);
  u16*   Yb    = (u16*)(wsb + 104 * MB);
  (void)ws_size; (void)in_sizes; (void)n_in; (void)out_size;

  cast_bf16<<<2048, 256, 0, stream>>>(X, Xb, 8192 * 1024 / 8);
  concat3<<<12, 256, 0, stream>>>(bq, bk, bv, bqkv);
  transpose_cast<<<dim3(32, 32), 256, 0, stream>>>(Wq, WqkvT, 1024, 1024, QSCALE);
  transpose_cast<<<dim3(32, 32), 256, 0, stream>>>(Wk, WqkvT + 1024 * 1024, 1024, 1024, 1.0f);
  transpose_cast<<<dim3(32, 32), 256, 0, stream>>>(Wv, WqkvT + 2 * 1024 * 1024, 1024, 1024, 1.0f);
  transpose_cast<<<dim3(32, 32), 256, 0, stream>>>(Wo, WoT, 1024, 1024, 1.0f);
  transpose_cast<<<dim3(128, 32), 256, 0, stream>>>(W1, W1T, 1024, 4096, 1.0f);
  transpose_cast<<<dim3(32, 128), 256, 0, stream>>>(W2, W2T, 4096, 1024, 1.0f);

  // fused QKV projection (Q pre-scaled): [8192,1024] @ [1024,3072]
  gemm8p<0><<<384, 512, 0, stream>>>(Xb, WqkvT, bqkv, QKVb, 8192, 3072, 1024, 12);

  vtrans<<<dim3(32, 16, 4), 256, 0, stream>>>(QKVb, Vt_g);
  attn_fwd<<<dim3(16, 16, 4), 256, 0, stream>>>(QKVb, QKVb + 1024, Vt_g, Cx, 3072);

  gemm8n<0><<<256, 512, 0, stream>>>(Cx, WoT, bo, Ab, 8192, 1024, 1024, 4);
  add_ln<1, 0><<<8192, 256, 0, stream>>>(X, Ab, g1, be1, Yb);
  gemm8p<1><<<512, 512, 0, stream>>>(Yb, W1T, b1, Hb, 8192, 4096, 1024, 16);
  gemm8n<0><<<256, 512, 0, stream>>>(Hb, W2T, b2, Fb, 8192, 1024, 4096, 4);
  add_ln<0, 1><<<8192, 256, 0, stream>>>(Yb, Fb, g2, be2, d_out);
}

// Round 19
// 402.702 us; speedup vs baseline: 1.0731x; 1.0314x over previous
//
#include <hip/hip_runtime.h>
#include <stdint.h>

typedef unsigned short u16;
typedef short bf16x8 __attribute__((ext_vector_type(8)));
typedef float f32x4 __attribute__((ext_vector_type(4)));
typedef float f32x16 __attribute__((ext_vector_type(16)));
typedef u16 u16x4 __attribute__((ext_vector_type(4)));
typedef u16 u16x8 __attribute__((ext_vector_type(8)));

#define LOG2E 1.4426950408889634f
#define QSCALE (0.125f * LOG2E)

__device__ __forceinline__ u16 f2bf(float f) {
  union { float f; uint32_t u; } x; x.f = f;
  uint32_t r = x.u + 0x7fffu + ((x.u >> 16) & 1u);
  return (u16)(r >> 16);
}
__device__ __forceinline__ u16 f2bf_ru(float f) {
  union { float f; uint32_t u; } x; x.f = f;
  return (u16)((x.u + 0x8000u) >> 16);
}
__device__ __forceinline__ float bf2f(u16 h) {
  union { uint32_t u; float f; } x; x.u = ((uint32_t)h) << 16;
  return x.f;
}
__device__ __forceinline__ uint32_t cvtpk(float lo, float hi) {
  uint32_t r;
  asm("v_cvt_pk_bf16_f32 %0, %1, %2" : "=v"(r) : "v"(lo), "v"(hi));
  return r;
}
// 16B-granule XOR swizzle (involution, low 3 bits of granule index)
__device__ __forceinline__ int swz3(int row) { return (row ^ (row >> 3)) & 7; }

__device__ __forceinline__ void gload_lds16(const void* g, void* lds) {
  __builtin_amdgcn_global_load_lds(
      (const __attribute__((address_space(1))) void*)g,
      (__attribute__((address_space(3))) void*)lds, 16, 0, 0);
}

// ---------------- fused prep: cast_bf16 + 6x transpose_cast + concat3 ----------------
// block ranges: [0,2048) cast X; [2048,6144) 4x 1024-block transposes (Wq/Wk/Wv/Wo);
// [6144,10240) W1T; [10240,14336) W2T; [14336,14348) concat3. Branch is
// block-uniform, so __syncthreads inside the transpose branch is safe.
__global__ __launch_bounds__(256) void prep(
    const float* __restrict__ X, u16* __restrict__ Xb,
    const float* __restrict__ Wq, const float* __restrict__ Wk,
    const float* __restrict__ Wv, const float* __restrict__ Wo,
    const float* __restrict__ W1, const float* __restrict__ W2,
    u16* __restrict__ WqkvT, u16* __restrict__ WoT,
    u16* __restrict__ W1T, u16* __restrict__ W2T,
    const float* __restrict__ bq, const float* __restrict__ bk,
    const float* __restrict__ bv, float* __restrict__ bqkv) {
  const int blk = blockIdx.x, t = threadIdx.x;
  if (blk < 2048) {
    // cast X f32 -> bf16, 8 elems/thread, grid-stride over n8 = 1048576
    const int n8 = 8192 * 1024 / 8;
    for (int i = blk * 256 + t; i < n8; i += 2048 * 256) {
      const f32x4* p = (const f32x4*)X + (size_t)i * 2;
      f32x4 a = p[0], b = p[1];
      u16x8 o;
      o[0] = f2bf(a[0]); o[1] = f2bf(a[1]); o[2] = f2bf(a[2]); o[3] = f2bf(a[3]);
      o[4] = f2bf(b[0]); o[5] = f2bf(b[1]); o[6] = f2bf(b[2]); o[7] = f2bf(b[3]);
      ((u16x8*)Xb)[i] = o;
    }
  } else if (blk < 14336) {
    const float* tin; u16* tout; int R, C; float sc; int bx, by;
    if (blk < 3072)      { tin = Wq; tout = WqkvT;                R = 1024; C = 1024; sc = QSCALE; bx = (blk - 2048) & 31;  by = (blk - 2048) >> 5; }
    else if (blk < 4096) { tin = Wk; tout = WqkvT + 1024 * 1024;  R = 1024; C = 1024; sc = 1.f;    bx = (blk - 3072) & 31;  by = (blk - 3072) >> 5; }
    else if (blk < 5120) { tin = Wv; tout = WqkvT + 2 * 1024 * 1024; R = 1024; C = 1024; sc = 1.f; bx = (blk - 4096) & 31;  by = (blk - 4096) >> 5; }
    else if (blk < 6144) { tin = Wo; tout = WoT;                  R = 1024; C = 1024; sc = 1.f;    bx = (blk - 5120) & 31;  by = (blk - 5120) >> 5; }
    else if (blk < 10240){ tin = W1; tout = W1T;                  R = 1024; C = 4096; sc = 1.f;    bx = (blk - 6144) & 127; by = (blk - 6144) >> 7; }
    else                 { tin = W2; tout = W2T;                  R = 4096; C = 1024; sc = 1.f;    bx = (blk - 10240) & 31; by = (blk - 10240) >> 5; }
    __shared__ float tile[32][33];
    const int bc = bx * 32, br = by * 32;
    const int tx = t & 31, ty = t >> 5;
#pragma unroll
    for (int i = 0; i < 32; i += 8)
      tile[ty + i][tx] = tin[(size_t)(br + ty + i) * C + bc + tx];
    __syncthreads();
#pragma unroll
    for (int i = 0; i < 32; i += 8)
      tout[(size_t)(bc + ty + i) * R + br + tx] = f2bf(tile[tx][ty + i] * sc);
  } else {
    const int i = (blk - 14336) * 256 + t;
    if (i < 3072)
      bqkv[i] = i < 1024 ? bq[i] * QSCALE : (i < 2048 ? bk[i - 1024] : bv[i - 2048]);
  }
}

// ---------------- GEMM 256x256, 4-phase + counted vmcnt, 32x32 MFMA ----------------
// VDUAL: blocks with n0 >= 2048 (V columns of the QKV gemm) additionally
// write the transposed copy into Vtg[(b*16+h)*64+dh][s] (u16x4 runs).
template <int RELU, int VDUAL>
__global__ __launch_bounds__(512, 2) void gemm8p(const u16* __restrict__ A,
                                                 const u16* __restrict__ BT,
                                                 const float* __restrict__ bias,
                                                 u16* __restrict__ Cb,
                                                 u16* __restrict__ Vtg,
                                                 int M, int N, int K, int nbx) {
  __shared__ u16 As[2][256 * 64];
  __shared__ u16 Bs[2][256 * 64];
  const int t = threadIdx.x;
  const int w = t >> 6, lane = t & 63;
  const int l5 = lane & 31, hf = lane >> 5;
  const int wr = w >> 2, wc = w & 3;
  int bid = (int)blockIdx.x;
  const int cpx = (int)gridDim.x >> 3;
  bid = (bid & 7) * cpx + (bid >> 3);
  const int m0 = (bid / nbx) * 256, n0 = (bid % nbx) * 256;
  const int NT = K >> 6;
  const int row64 = t >> 3;
  const int colp = ((t & 7) ^ swz3(row64)) << 3;

#define STG_A(buf, tile, q) \
  gload_lds16(A + (size_t)(m0 + (q)*64 + row64) * K + ((tile) << 6) + colp, \
              &As[buf][(q)*4096 + w * 512])
#define STG_B(buf, tile, q) \
  gload_lds16(BT + (size_t)(n0 + (q)*64 + row64) * K + ((tile) << 6) + colp, \
              &Bs[buf][(q)*4096 + w * 512])
#define LDA32(dst, mfi, kb) { const int r_ = wr * 128 + (mfi)*32 + l5; \
  dst = *(const bf16x8*)&As[cur][r_ * 64 + (((((kb) << 1) + hf) ^ swz3(r_)) << 3)]; }
#define LDB32(dst, nfi, kb) { const int r_ = wc * 64 + (nfi)*32 + l5; \
  dst = *(const bf16x8*)&Bs[cur][r_ * 64 + (((((kb) << 1) + hf) ^ swz3(r_)) << 3)]; }
#define MFMA32(mh, nfi, barr) \
  __builtin_amdgcn_s_setprio(1); \
  _Pragma("unroll") for (int kb = 0; kb < 4; kb++) \
  _Pragma("unroll") for (int i = 0; i < 2; i++) \
    acc[((mh)*2 + i) * 2 + (nfi)] = __builtin_amdgcn_mfma_f32_32x32x16_bf16( \
        af[i][kb], barr[kb], acc[((mh)*2 + i) * 2 + (nfi)], 0, 0, 0); \
  __builtin_amdgcn_s_setprio(0);
#define BAR1() __builtin_amdgcn_s_barrier(); \
  asm volatile("s_waitcnt lgkmcnt(0)" ::: "memory"); \
  __builtin_amdgcn_sched_barrier(0)

  f32x16 acc[8];
#pragma unroll
  for (int i = 0; i < 8; i++)
#pragma unroll
    for (int j = 0; j < 16; j++) acc[i][j] = 0.f;

  STG_A(0, 0, 0); STG_A(0, 0, 2);
  STG_B(0, 0, 0); STG_B(0, 0, 1); STG_B(0, 0, 2); STG_B(0, 0, 3);
  STG_A(0, 0, 1); STG_A(0, 0, 3);
  asm volatile("s_waitcnt vmcnt(2)" ::: "memory");
  __builtin_amdgcn_s_barrier();

  for (int tile = 0; tile < NT; ++tile) {
    const int cur = tile & 1, nxt = cur ^ 1;
    const bool hn = (tile + 1) < NT;
    bf16x8 af[2][4], b0[4], b1[4];
#pragma unroll
    for (int kb = 0; kb < 4; kb++) { LDA32(af[0][kb], 0, kb); LDA32(af[1][kb], 1, kb); }
#pragma unroll
    for (int kb = 0; kb < 4; kb++) { LDB32(b0[kb], 0, kb); }
    if (hn) { STG_A(nxt, tile + 1, 0); STG_A(nxt, tile + 1, 2); }
    BAR1();
    MFMA32(0, 0, b0);
    __builtin_amdgcn_s_barrier();
#pragma unroll
    for (int kb = 0; kb < 4; kb++) { LDB32(b1[kb], 1, kb); }
    if (hn) { STG_B(nxt, tile + 1, 0); STG_B(nxt, tile + 1, 1); }
    BAR1();
    MFMA32(0, 1, b1);
    if (hn) { asm volatile("s_waitcnt vmcnt(4)" ::: "memory"); }
    else    { asm volatile("s_waitcnt vmcnt(0)" ::: "memory"); }
    __builtin_amdgcn_s_barrier();
#pragma unroll
    for (int kb = 0; kb < 4; kb++) { LDA32(af[0][kb], 2, kb); LDA32(af[1][kb], 3, kb); }
    if (hn) { STG_B(nxt, tile + 1, 2); STG_B(nxt, tile + 1, 3); }
    BAR1();
    MFMA32(1, 0, b0);
    __builtin_amdgcn_s_barrier();
    if (hn) { STG_A(nxt, tile + 1, 1); STG_A(nxt, tile + 1, 3); }
    BAR1();
    MFMA32(1, 1, b1);
    if (hn) { asm volatile("s_waitcnt vmcnt(2)" ::: "memory"); }
    __builtin_amdgcn_s_barrier();
  }
#undef STG_A
#undef STG_B
#undef LDA32
#undef LDB32
#undef MFMA32
#undef BAR1

#pragma unroll
  for (int mf = 0; mf < 4; mf++) {
#pragma unroll
    for (int nf = 0; nf < 2; nf++) {
      const int c = n0 + wc * 64 + nf * 32 + l5;
      const float bv = bias[c];
      u16 vals[16];
#pragma unroll
      for (int reg = 0; reg < 16; reg++) {
        const int r = m0 + wr * 128 + mf * 32 + (reg & 3) + 8 * (reg >> 2) + 4 * hf;
        float v = acc[mf * 2 + nf][reg] + bv;
        if (RELU) v = fmaxf(v, 0.f);
        vals[reg] = f2bf(v);
        Cb[(size_t)r * N + c] = vals[reg];
      }
      if (VDUAL && n0 >= 2048) {
        const int h = (c - 2048) >> 6, dh = (c - 2048) & 63;
#pragma unroll
        for (int rg = 0; rg < 4; rg++) {
          const int r0 = m0 + wr * 128 + mf * 32 + rg * 8 + 4 * hf;
          const int b = r0 >> 11, s = r0 & 2047;
          u16x4 o;
#pragma unroll
          for (int e = 0; e < 4; e++) o[e] = vals[rg * 4 + e];
          *(u16x4*)&Vtg[((size_t)(b * 16 + h) * 64 + dh) * 2048 + s] = o;
        }
      }
    }
  }
}

// ---------------- GEMM 128x256, 2-phase + counted vmcnt, 32x32 MFMA ----------------
template <int RELU>
__global__ __launch_bounds__(512, 2) void gemm8n(const u16* __restrict__ A,
                                                 const u16* __restrict__ BT,
                                                 const float* __restrict__ bias,
                                                 u16* __restrict__ Cb,
                                                 int M, int N, int K, int nbx) {
  __shared__ u16 As[2][128 * 64];
  __shared__ u16 Bs[2][256 * 64];
  const int t = threadIdx.x;
  const int w = t >> 6, lane = t & 63;
  const int l5 = lane & 31, hf = lane >> 5;
  const int wr = w >> 2, wc = w & 3;
  int bid = (int)blockIdx.x;
  const int cpx = (int)gridDim.x >> 3;
  bid = (bid & 7) * cpx + (bid >> 3);
  const int m0 = (bid / nbx) * 128, n0 = (bid % nbx) * 256;
  const int NT = K >> 6;
  const int rowA = t >> 3;
  const int colpA = ((t & 7) ^ swz3(rowA)) << 3;

#define STG_An(buf, tile, q) \
  gload_lds16(A + (size_t)(m0 + (q)*64 + rowA) * K + ((tile) << 6) + colpA, \
              &As[buf][(q)*4096 + t * 8])
#define STG_Bn(buf, tile, c, i) { \
  const int r32_ = (i)*64 + (t >> 3); \
  const int R_ = ((r32_ >> 5) << 6) + (c)*32 + (r32_ & 31); \
  const int cp_ = ((t & 7) ^ swz3(R_)) << 3; \
  gload_lds16(BT + (size_t)(n0 + R_) * K + ((tile) << 6) + cp_, \
              &Bs[buf][R_ * 64 + (t & 7) * 8]); }
#define LDAn(dst, mfi, kb) { const int r_ = wr * 64 + (mfi)*32 + l5; \
  dst = *(const bf16x8*)&As[cur][r_ * 64 + (((((kb) << 1) + hf) ^ swz3(r_)) << 3)]; }
#define LDBn(dst, nfi, kb) { const int r_ = wc * 64 + (nfi)*32 + l5; \
  dst = *(const bf16x8*)&Bs[cur][r_ * 64 + (((((kb) << 1) + hf) ^ swz3(r_)) << 3)]; }
#define MFMAn(nfi, barr) \
  __builtin_amdgcn_s_setprio(1); \
  _Pragma("unroll") for (int kb = 0; kb < 4; kb++) \
  _Pragma("unroll") for (int i = 0; i < 2; i++) \
    acc[i * 2 + (nfi)] = __builtin_amdgcn_mfma_f32_32x32x16_bf16( \
        af[i][kb], barr[kb], acc[i * 2 + (nfi)], 0, 0, 0); \
  __builtin_amdgcn_s_setprio(0);
#define BARn() __builtin_amdgcn_s_barrier(); \
  asm volatile("s_waitcnt lgkmcnt(0)" ::: "memory"); \
  __builtin_amdgcn_sched_barrier(0)

  f32x16 acc[4];
#pragma unroll
  for (int i = 0; i < 4; i++)
#pragma unroll
    for (int j = 0; j < 16; j++) acc[i][j] = 0.f;

  STG_Bn(0, 0, 0, 0); STG_Bn(0, 0, 0, 1); STG_An(0, 0, 0);
  STG_An(0, 0, 1); STG_Bn(0, 0, 1, 0); STG_Bn(0, 0, 1, 1);
  asm volatile("s_waitcnt vmcnt(0)" ::: "memory");
  __builtin_amdgcn_s_barrier();

  for (int tile = 0; tile < NT; ++tile) {
    const int cur = tile & 1, nxt = cur ^ 1;
    const bool hn = (tile + 1) < NT;
    bf16x8 af[2][4], b0[4], b1[4];
#pragma unroll
    for (int kb = 0; kb < 4; kb++) { LDAn(af[0][kb], 0, kb); LDAn(af[1][kb], 1, kb); }
#pragma unroll
    for (int kb = 0; kb < 4; kb++) { LDBn(b0[kb], 0, kb); }
    if (hn) { STG_Bn(nxt, tile + 1, 0, 0); STG_Bn(nxt, tile + 1, 0, 1); STG_An(nxt, tile + 1, 0); }
    BARn();
    MFMAn(0, b0);
    if (hn) { asm volatile("s_waitcnt vmcnt(3)" ::: "memory"); }
    else    { asm volatile("s_waitcnt vmcnt(0)" ::: "memory"); }
    __builtin_amdgcn_s_barrier();
#pragma unroll
    for (int kb = 0; kb < 4; kb++) { LDBn(b1[kb], 1, kb); }
    if (hn) { STG_An(nxt, tile + 1, 1); STG_Bn(nxt, tile + 1, 1, 0); STG_Bn(nxt, tile + 1, 1, 1); }
    BARn();
    MFMAn(1, b1);
    if (hn) { asm volatile("s_waitcnt vmcnt(2)" ::: "memory"); }
    __builtin_amdgcn_s_barrier();
  }
#undef STG_An
#undef STG_Bn
#undef LDAn
#undef LDBn
#undef MFMAn
#undef BARn

#pragma unroll
  for (int mf = 0; mf < 2; mf++) {
#pragma unroll
    for (int nf = 0; nf < 2; nf++) {
      const int c = n0 + wc * 64 + nf * 32 + l5;
      const float bv = bias[c];
#pragma unroll
      for (int reg = 0; reg < 16; reg++) {
        const int r = m0 + wr * 64 + mf * 32 + (reg & 3) + 8 * (reg >> 2) + 4 * hf;
        float v = acc[mf * 2 + nf][reg] + bv;
        if (RELU) v = fmaxf(v, 0.f);
        Cb[(size_t)r * N + c] = f2bf(v);
      }
    }
  }
}

// ---------------- flash attention fwd (32x32 MFMA, permlane exchange) ----------------
// Row-max stays a SERIAL fmax chain: tree variant measured 5 us slower (r17).
__global__ __launch_bounds__(256, 3) void attn_fwd(const u16* __restrict__ Qg,
                                                   const u16* __restrict__ Kg,
                                                   const u16* __restrict__ Vtg,
                                                   u16* __restrict__ Og, int LDM) {
  constexpr int S = 2048, DMO = 1024, NT = S / 64;
  __shared__ u16 Ks[2][64 * 64];
  __shared__ u16 Vt[2][64 * 64];
  const int t = threadIdx.x, w = t >> 6, lane = t & 63;
  const int l5 = lane & 31, hf = lane >> 5;
  const int qb = blockIdx.x, h = blockIdx.y, b = blockIdx.z;
  const size_t base = ((size_t)b * S) * LDM + h * 64;
  const size_t vbase = ((size_t)(b * 16 + h) * 64) * 2048;
  const size_t obase = ((size_t)b * S) * DMO + h * 64;
  const int qrow0 = qb * 128 + w * 32;

#define ATT_STAGE(buf, kt_) { \
  _Pragma("unroll") for (int i = 0; i < 2; i++) { \
    const int s = i * 256 + t; const int r = s >> 3; const int cg = s & 7; \
    gload_lds16(Kg + base + (size_t)((kt_) + r) * LDM + ((cg ^ swz3(r)) << 3), \
                &Ks[buf][s * 8]); } \
  _Pragma("unroll") for (int i = 0; i < 2; i++) { \
    const int s = i * 256 + t; const int r = s >> 3; const int cg = s & 7; \
    gload_lds16(Vtg + vbase + (size_t)r * 2048 + (kt_) + ((cg ^ swz3(r)) << 3), \
                &Vt[buf][s * 8]); } }

  bf16x8 qf[4];
#pragma unroll
  for (int kb = 0; kb < 4; kb++)
    qf[kb] = *(const bf16x8*)&Qg[base + (size_t)(qrow0 + l5) * LDM + kb * 16 + hf * 8];

  f32x16 accO0, accO1, accL;
#pragma unroll
  for (int i = 0; i < 16; i++) { accO0[i] = 0.f; accO1[i] = 0.f; accL[i] = 0.f; }
  float m = -1e30f;

  bf16x8 ones;
#pragma unroll
  for (int i = 0; i < 8; i++) ones[i] = (short)0x3F80;  // bf16 1.0

  ATT_STAGE(0, 0);
  asm volatile("s_waitcnt vmcnt(0)" ::: "memory");
  __builtin_amdgcn_s_barrier();

  for (int kt = 0; kt < NT; ++kt) {
    const int cur = kt & 1;
    if (kt + 1 < NT) ATT_STAGE(cur ^ 1, (kt + 1) * 64);

    f32x16 st0, st1;
#pragma unroll
    for (int i = 0; i < 16; i++) { st0[i] = 0.f; st1[i] = 0.f; }
    __builtin_amdgcn_s_setprio(1);
#pragma unroll
    for (int kb = 0; kb < 4; kb++) {
      const int r0 = l5, r1 = 32 + l5;
      bf16x8 kf0 = *(const bf16x8*)&Ks[cur][r0 * 64 + (((hf + 2 * kb) ^ swz3(r0)) << 3)];
      bf16x8 kf1 = *(const bf16x8*)&Ks[cur][r1 * 64 + (((hf + 2 * kb) ^ swz3(r1)) << 3)];
      st0 = __builtin_amdgcn_mfma_f32_32x32x16_bf16(kf0, qf[kb], st0, 0, 0, 0);
      st1 = __builtin_amdgcn_mfma_f32_32x32x16_bf16(kf1, qf[kb], st1, 0, 0, 0);
    }
    __builtin_amdgcn_s_setprio(0);

    float rm = st0[0];
#pragma unroll
    for (int i = 1; i < 16; i++) rm = fmaxf(rm, st0[i]);
#pragma unroll
    for (int i = 0; i < 16; i++) rm = fmaxf(rm, st1[i]);
    if (__any(rm > m + 8.0f)) {  // defer-max THR=8 (log2 units)
      float ra = rm, rb = rm;
      asm volatile("v_permlane32_swap_b32 %0, %1" : "+v"(ra), "+v"(rb));
      rm = fmaxf(rm, fmaxf(ra, rb));
      const float mN = fmaxf(m, rm);
      const float al = exp2f(m - mN);
      m = mN;
#pragma unroll
      for (int r = 0; r < 16; r++) {
        const float alr = __shfl(al, (r & 3) + 8 * (r >> 2) + 4 * hf, 64);
        accO0[r] *= alr; accO1[r] *= alr; accL[r] *= alr;
      }
    }

    uint32_t pw0[8], pw1[8];
#pragma unroll
    for (int r2 = 0; r2 < 8; r2++) {
      pw0[r2] = cvtpk(exp2f(st0[2 * r2] - m), exp2f(st0[2 * r2 + 1] - m));
      pw1[r2] = cvtpk(exp2f(st1[2 * r2] - m), exp2f(st1[2 * r2 + 1] - m));
    }
    bf16x8 pf[4];
    {
      uint32_t a0 = pw0[0], b0v = pw0[2], a1 = pw0[1], b1v = pw0[3];
      asm volatile("v_permlane32_swap_b32 %0, %1" : "+v"(a0), "+v"(b0v));
      asm volatile("v_permlane32_swap_b32 %0, %1" : "+v"(a1), "+v"(b1v));
      union { uint32_t u[4]; bf16x8 v; } k;
      k.u[0] = a0; k.u[1] = a1; k.u[2] = b0v; k.u[3] = b1v; pf[0] = k.v;
      uint32_t c0 = pw0[4], d0 = pw0[6], c1 = pw0[5], d1 = pw0[7];
      asm volatile("v_permlane32_swap_b32 %0, %1" : "+v"(c0), "+v"(d0));
      asm volatile("v_permlane32_swap_b32 %0, %1" : "+v"(c1), "+v"(d1));
      k.u[0] = c0; k.u[1] = c1; k.u[2] = d0; k.u[3] = d1; pf[1] = k.v;
      uint32_t e0 = pw1[0], f0 = pw1[2], e1 = pw1[1], f1 = pw1[3];
      asm volatile("v_permlane32_swap_b32 %0, %1" : "+v"(e0), "+v"(f0));
      asm volatile("v_permlane32_swap_b32 %0, %1" : "+v"(e1), "+v"(f1));
      k.u[0] = e0; k.u[1] = e1; k.u[2] = f0; k.u[3] = f1; pf[2] = k.v;
      uint32_t g0 = pw1[4], h0 = pw1[6], g1 = pw1[5], h1 = pw1[7];
      asm volatile("v_permlane32_swap_b32 %0, %1" : "+v"(g0), "+v"(h0));
      asm volatile("v_permlane32_swap_b32 %0, %1" : "+v"(g1), "+v"(h1));
      k.u[0] = g0; k.u[1] = g1; k.u[2] = h0; k.u[3] = h1; pf[3] = k.v;
    }

    __builtin_amdgcn_s_setprio(1);
#pragma unroll
    for (int kb = 0; kb < 4; kb++) {
      const int r0 = l5, r1 = 32 + l5;
      bf16x8 vf0 = *(const bf16x8*)&Vt[cur][r0 * 64 + (((hf + 2 * kb) ^ swz3(r0)) << 3)];
      bf16x8 vf1 = *(const bf16x8*)&Vt[cur][r1 * 64 + (((hf + 2 * kb) ^ swz3(r1)) << 3)];
      accO0 = __builtin_amdgcn_mfma_f32_32x32x16_bf16(pf[kb], vf0, accO0, 0, 0, 0);
      accO1 = __builtin_amdgcn_mfma_f32_32x32x16_bf16(pf[kb], vf1, accO1, 0, 0, 0);
      accL  = __builtin_amdgcn_mfma_f32_32x32x16_bf16(pf[kb], ones, accL, 0, 0, 0);
    }
    __builtin_amdgcn_s_setprio(0);

    asm volatile("s_waitcnt vmcnt(0)" ::: "memory");
    __builtin_amdgcn_s_barrier();
  }
#undef ATT_STAGE

#pragma unroll
  for (int r = 0; r < 16; r++) {
    const float inv = 1.0f / accL[r];
    const int row = qrow0 + (r & 3) + 8 * (r >> 2) + 4 * hf;
    Og[obase + (size_t)row * DMO + l5]      = f2bf_ru(accO0[r] * inv);
    Og[obase + (size_t)row * DMO + 32 + l5] = f2bf_ru(accO1[r] * inv);
  }
}

// ---------------- fused residual-add + LayerNorm (D=1024) ----------------
template <int AF32, int OUTF32>
__global__ __launch_bounds__(256) void add_ln(const void* __restrict__ Ap,
                                              const u16* __restrict__ Bb,
                                              const float* __restrict__ g,
                                              const float* __restrict__ be,
                                              void* __restrict__ Yp) {
  constexpr int D = 1024;
  const int row = blockIdx.x, t = threadIdx.x;
  f32x4 a;
  if (AF32) {
    a = ((const f32x4*)((const float*)Ap + (size_t)row * D))[t];
  } else {
    u16x4 av = ((const u16x4*)((const u16*)Ap + (size_t)row * D))[t];
#pragma unroll
    for (int i = 0; i < 4; i++) a[i] = bf2f(av[i]);
  }
  u16x4 bv16 = ((const u16x4*)(Bb + (size_t)row * D))[t];
  f32x4 x;
#pragma unroll
  for (int i = 0; i < 4; i++) x[i] = a[i] + bf2f(bv16[i]);
  float s1 = x[0] + x[1] + x[2] + x[3];
  float s2 = x[0] * x[0] + x[1] * x[1] + x[2] * x[2] + x[3] * x[3];
#pragma unroll
  for (int off = 32; off > 0; off >>= 1) {
    s1 += __shfl_down(s1, off, 64);
    s2 += __shfl_down(s2, off, 64);
  }
  __shared__ float sm[8];
  const int w = t >> 6, lane = t & 63;
  if (lane == 0) { sm[w] = s1; sm[4 + w] = s2; }
  __syncthreads();
  s1 = sm[0] + sm[1] + sm[2] + sm[3];
  s2 = sm[4] + sm[5] + sm[6] + sm[7];
  const float mean = s1 * (1.0f / D);
  const float var = s2 * (1.0f / D) - mean * mean;
  const float rstd = rsqrtf(var + 1e-5f);
  const f32x4 gv = ((const f32x4*)g)[t];
  const f32x4 bv = ((const f32x4*)be)[t];
  f32x4 y;
#pragma unroll
  for (int i = 0; i < 4; i++) y[i] = (x[i] - mean) * rstd * gv[i] + bv[i];
  if (OUTF32) {
    ((f32x4*)((float*)Yp + (size_t)row * D))[t] = y;
  } else {
    u16x4 o;
#pragma unroll
    for (int i = 0; i < 4; i++) o[i] = f2bf(y[i]);
    ((u16x4*)((u16*)Yp + (size_t)row * D))[t] = o;
  }
}

extern "C" void kernel_launch(void* const* d_in, const int* in_sizes, int n_in,
                              void* d_out, int out_size, void* d_ws, size_t ws_size,
                              hipStream_t stream) {
  const float* X   = (const float*)d_in[0];
  const float* Wq  = (const float*)d_in[1];
  const float* bq  = (const float*)d_in[2];
  const float* Wk  = (const float*)d_in[3];
  const float* bk  = (const float*)d_in[4];
  const float* Wv  = (const float*)d_in[5];
  const float* bv  = (const float*)d_in[6];
  const float* Wo  = (const float*)d_in[7];
  const float* bo  = (const float*)d_in[8];
  const float* g1  = (const float*)d_in[9];
  const float* be1 = (const float*)d_in[10];
  const float* W1  = (const float*)d_in[11];
  const float* b1  = (const float*)d_in[12];
  const float* W2  = (const float*)d_in[13];
  const float* b2  = (const float*)d_in[14];
  const float* g2  = (const float*)d_in[15];
  const float* be2 = (const float*)d_in[16];

  // ---- workspace plan (peak 120 MB, lifetime-aliased) ----
  const size_t MB = 1ull << 20;
  char* wsb = (char*)d_ws;
  u16*   WqkvT = (u16*)(wsb + 0 * MB);
  u16*   WoT   = (u16*)(wsb + 6 * MB);
  u16*   W1T   = (u16*)(wsb + 8 * MB);
  u16*   W2T   = (u16*)(wsb + 16 * MB);
  u16*   Xb    = (u16*)(wsb + 24 * MB);
  u16*   Ab    = (u16*)(wsb + 24 * MB);
  u16*   Fb    = (u16*)(wsb + 24 * MB);
  u16*   QKVb  = (u16*)(wsb + 40 * MB);
  u16*   Hb    = (u16*)(wsb + 40 * MB);
  float* bqkv  = (float*)(wsb + 88 * MB);
  u16*   Cx    = (u16*)(wsb + 88 * MB);
  u16*   Vt_g  = (u16*)(wsb + 104 * MB);
  u16*   Yb    = (u16*)(wsb + 104 * MB);
  (void)ws_size; (void)in_sizes; (void)n_in; (void)out_size;

  // fused prep: cast + 6 weight transposes + bias concat (1 launch, was 8)
  prep<<<14348, 256, 0, stream>>>(X, Xb, Wq, Wk, Wv, Wo, W1, W2,
                                  WqkvT, WoT, W1T, W2T, bq, bk, bv, bqkv);

  // fused QKV projection (Q pre-scaled); V columns dual-written transposed
  gemm8p<0, 1><<<384, 512, 0, stream>>>(Xb, WqkvT, bqkv, QKVb, Vt_g, 8192, 3072, 1024, 12);

  attn_fwd<<<dim3(16, 16, 4), 256, 0, stream>>>(QKVb, QKVb + 1024, Vt_g, Cx, 3072);

  gemm8n<0><<<256, 512, 0, stream>>>(Cx, WoT, bo, Ab, 8192, 1024, 1024, 4);
  add_ln<1, 0><<<8192, 256, 0, stream>>>(X, Ab, g1, be1, Yb);
  gemm8p<1, 0><<<512, 512, 0, stream>>>(Yb, W1T, b1, Hb, nullptr, 8192, 4096, 1024, 16);
  gemm8n<0><<<256, 512, 0, stream>>>(Hb, W2T, b2, Fb, 8192, 1024, 4096, 4);
  add_ln<0, 1><<<8192, 256, 0, stream>>>(Yb, Fb, g2, be2, d_out);
}